// Round 8
// baseline (269.384 us; speedup 1.0000x reference)
//
#include <hip/hip_runtime.h>

// dense_image_warp: B=8, H=512, W=512, C=16, fp32.
//
// R7: LDS-staged tiles -- remove the scattered-VMEM gather path.
// Evidence chain: locality fixes (R1 nt-store, R3 2D tiles+XCD swizzle) null;
// MLP increase (R4) regressed; 128B pair-merge (R5) null (=> 64B L1 lines).
// Everything points at TA/TCP scattered-line throughput (~4-5 cy per scattered
// 64B line, ~4.3 lines/px => ~70-80us) as the binder; HBM 33%, VALU <=20%,
// LDS 0 all slack.
// Fix: block = 16x16 pixel tile (1024 threads, [yy:4][xx:4][cg:2]). Stage the
// 28x28-px slab (R=6 halo, 49KB) into LDS with dense coalesced float4 streams
// (3.06x amplification but contiguous = fast TA case), then gather corners
// from LDS. Flow is N(0,1) (max ~5.5 over 4.2M draws) so R=6 covers all
// gathers; a predicated global-load fallback keeps exact correctness anyway.
// XCD-chunked swizzle kept (8192 blocks %8==0, bijective): halo re-reads of
// neighboring tiles stay in one XCD's L2.

#define RAD 6
#define TS  16
#define SW  (TS + 2*RAD)          // 28 slab pixels per side
#define SF4 (SW*SW*4)             // 3136 float4 slots = 49KB

__global__ __launch_bounds__(1024) void warp_kernel(
    const float* __restrict__ img,
    const float* __restrict__ flow,
    float* __restrict__ out)
{
    __shared__ float4 slab[SF4];

    // XCD-chunked bijective swizzle (8192 blocks, 8 XCDs)
    const int bid = blockIdx.x;
    const int logical = ((bid & 7) << 10) + (bid >> 3);
    const int tx = logical & 31;          // tile x: 0..31
    const int ty = (logical >> 5) & 31;   // tile y: 0..31
    const int b  = logical >> 10;         // batch: 0..7

    const int x0 = tx << 4, y0 = ty << 4;
    const int ox = x0 - RAD, oy = y0 - RAD;

    // ---- per-thread flow load + address math (independent of LDS; issue early)
    const int t  = threadIdx.x;
    const int cg = t & 3;
    const int xx = (t >> 2) & 15;
    const int yy = t >> 6;
    const int x = x0 + xx, y = y0 + yy;
    const int pix = (((b << 9) + y) << 9) + x;

    const float2 f = ((const float2*)flow)[pix];
    const float qy = (float)y - f.x;
    const float qx = (float)x - f.y;
    float fy = floorf(qy); fy = fminf(fmaxf(fy, 0.0f), 510.0f);
    float fx = floorf(qx); fx = fminf(fmaxf(fx, 0.0f), 510.0f);
    const float ay = fminf(fmaxf(qy - fy, 0.0f), 1.0f);
    const float ax = fminf(fmaxf(qx - fx, 0.0f), 1.0f);
    const int iy = (int)fy;
    const int ix = (int)fx;

    // ---- stage slab: dense coalesced float4 streams, 112 float4 per slab row
    const float4* img4 = (const float4*)img;
    for (int l = t; l < SF4; l += 1024) {
        const int row = l / (SW * 4);
        const int u   = l - row * (SW * 4);    // 0..111
        const int gy  = oy + row;
        const int gx  = ox + (u >> 2);
        if ((unsigned)gy < 512u && (unsigned)gx < 512u) {
            slab[l] = img4[((((((b << 9) + gy) << 9) + gx)) << 2) + (u & 3)];
        }
    }
    __syncthreads();

    // ---- gather corners (LDS fast path; global fallback never taken for N(0,1) flow)
    const int ry = iy - oy;
    const int rx = ix - ox;
    float4 tl, tr, bl, br;
    if ((unsigned)ry <= (unsigned)(SW - 2) && (unsigned)rx <= (unsigned)(SW - 2)) {
        const int s = (ry * SW + rx) * 4 + cg;
        tl = slab[s];
        tr = slab[s + 4];
        bl = slab[s + SW * 4];
        br = slab[s + SW * 4 + 4];
    } else {
        const float* p = img + ((size_t)((((b << 9) + iy) << 9) + ix)) * 16 + (cg << 2);
        tl = *(const float4*)(p);
        tr = *(const float4*)(p + 16);
        bl = *(const float4*)(p + 512 * 16);
        br = *(const float4*)(p + 512 * 16 + 16);
    }

    float4 r;
    {
        float t0, u0;
        t0 = tl.x + ax * (tr.x - tl.x);
        u0 = bl.x + ax * (br.x - bl.x);
        r.x = t0 + ay * (u0 - t0);
        t0 = tl.y + ax * (tr.y - tl.y);
        u0 = bl.y + ax * (br.y - bl.y);
        r.y = t0 + ay * (u0 - t0);
        t0 = tl.z + ax * (tr.z - tl.z);
        u0 = bl.z + ax * (br.z - bl.z);
        r.z = t0 + ay * (u0 - t0);
        t0 = tl.w + ax * (tr.w - tl.w);
        u0 = bl.w + ax * (br.w - bl.w);
        r.w = t0 + ay * (u0 - t0);
    }

    ((float4*)out)[(pix << 2) + cg] = r;
}

extern "C" void kernel_launch(void* const* d_in, const int* in_sizes, int n_in,
                              void* d_out, int out_size, void* d_ws, size_t ws_size,
                              hipStream_t stream) {
    const float* img  = (const float*)d_in[0];
    const float* flow = (const float*)d_in[1];
    float* out = (float*)d_out;

    const int block = 1024;                       // 16x16 pixel tile, 4 cg/pixel
    const int grid = (8 * 512 * 512 * 4) / block; // 8192
    warp_kernel<<<grid, block, 0, stream>>>(img, flow, out);
}